// Round 8
// baseline (130.028 us; speedup 1.0000x reference)
//
#include <hip/hip_runtime.h>
#include <math.h>

#define NB 1024
#define NR 512
#define ND 256
#define XS_STRIDE 260   // mult of 4: 16B-aligned rows for ds_read_b128; 0 conflicts measured (r6)

typedef float v4f __attribute__((ext_vector_type(4)));

constexpr float kBETA  = 6.0f;
constexpr float kLOG2E = 1.4426950408889634f;

#if __has_builtin(__builtin_amdgcn_exp2f)
__device__ __forceinline__ float fast_exp2(float x) { return __builtin_amdgcn_exp2f(x); }
#else
__device__ __forceinline__ float fast_exp2(float x) { return exp2f(x); }
#endif
#if __has_builtin(__builtin_amdgcn_rcpf)
__device__ __forceinline__ float fast_rcp(float x) { return __builtin_amdgcn_rcpf(x); }
#else
__device__ __forceinline__ float fast_rcp(float x) { return 1.0f / x; }
#endif

__device__ __forceinline__ float fast_sigmoid(float a) {   // 1/(1+e^-a)
    return fast_rcp(1.0f + fast_exp2(-a * kLOG2E));
}
__device__ __forceinline__ float fast_tanh(float a) {      // 1 - 2/(1+e^{2a})
    return 1.0f - 2.0f * fast_rcp(1.0f + fast_exp2(a * (2.0f * kLOG2E)));
}

// uniform-lane broadcast via v_readlane (result lands in SGPRs)
__device__ __forceinline__ float rl(float v, int l) {
    return __uint_as_float(__builtin_amdgcn_readlane(__float_as_uint(v), l));
}

// Prep: P4[r*ND+d] = {E, K, A1, A0} with b = Xe*E (separable exp):
//   E  = exp2(-s*t_high), K = exp2(-s*width)
//   element term (vs baseR): (A1*b + A0) / ((b+1)(b+K))
//   A1 = meh - mel*K, A0 = K*(meh - mel)
// baseR[r] = sum_d (meh - mel); evidence = baseR - 2*sum(term)
__global__ __launch_bounds__(256) void prep_kernel(
    const float* __restrict__ center, const float* __restrict__ log_width,
    const float* __restrict__ e_low, const float* __restrict__ e_high,
    const float* __restrict__ mask, const float* __restrict__ log_kappa,
    const float* __restrict__ head_b,
    float4* __restrict__ P4, float* __restrict__ baseR, float* __restrict__ y)
{
    const int r = blockIdx.x;
    const int d = threadIdx.x;
    const int idx = r * ND + d;

    const float kappa = fminf(fmaxf(fast_exp2(log_kappa[0] * kLOG2E), 0.5f), 50.0f);
    const float s = kappa * kLOG2E;

    const float wdt = fminf(fmaxf(fast_exp2(log_width[idx] * kLOG2E), 0.001f), 50.0f);
    const float th  = center[idx] + 0.5f * wdt;
    const float E   = fast_exp2(-s * th);
    const float K   = fmaxf(fast_exp2(-s * wdt), 1e-30f);   // floor: keeps den > 0
    const float m   = fast_sigmoid(mask[idx]);
    const float mel = m * fast_tanh(e_low[idx]);
    const float meh = m * fast_tanh(e_high[idx]);

    float4 p;
    p.x = E;
    p.y = K;
    p.z = fmaf(-mel, K, meh);      // A1
    p.w = K * (meh - mel);         // A0
    P4[idx] = p;

    float v = meh - mel;
    #pragma unroll
    for (int off = 32; off > 0; off >>= 1) v += __shfl_down(v, off, 64);
    __shared__ float red[4];
    if ((d & 63) == 0) red[d >> 6] = v;
    __syncthreads();
    if (d == 0) baseR[r] = red[0] + red[1] + red[2] + red[3];

    const int gid = blockIdx.x * 256 + threadIdx.x;
    if (gid < NB) y[gid] = head_b[0];
}

// Fused pair (2 elems, 10 VALU + 1 rcp):
//   per elem: b = X*E; q = b+K; den = q*b+q; num = A1*b+A0
//   acc += (num1*den2 + num2*den1) * rcp(den1*den2)
// Xe clamped to 2^+-14 in staging => den1*den2 bounded, no overflow.
__device__ __forceinline__ void pairstep(const float X1, const float X2,
                                         const float4 p1, const float4 p2,
                                         float& acc)
{
    const float b1   = X1 * p1.x;
    const float b2   = X2 * p2.x;
    const float q1   = b1 + p1.y;
    const float q2   = b2 + p2.y;
    const float den1 = fmaf(q1, b1, q1);
    const float den2 = fmaf(q2, b2, q2);
    const float num1 = fmaf(p1.z, b1, p1.w);
    const float num2 = fmaf(p2.z, b2, p2.w);
    const float nn   = fmaf(num2, den1, num1 * den2);
    const float dd   = den1 * den2;
    acc = fmaf(nn, fast_rcp(dd), acc);
}

// Main: lane=b mapping (in-lane d-reduction, r3-6) + P-in-VGPRs (r7), bridged
// by v_readlane broadcast. 1024 threads = 16 waves; wave w -> r; lane = b.
// Lane t holds P4[r][4t..4t+3] (16 VGPRs). Iter t: whole wave broadcasts lane
// t's params (16 readlanes -> SGPRs) + 1 ds_read_b128 of own X row. The loop
// has ZERO scalar-memory and ZERO global loads.
__global__ __launch_bounds__(1024, 8) void evid_kernel(
    const float* __restrict__ x, const float* __restrict__ log_kappa,
    const float* __restrict__ t_arr, const float* __restrict__ head_w,
    const float4* __restrict__ P4, const float* __restrict__ baseR,
    float* __restrict__ y)
{
    __shared__ float xs[64 * XS_STRIDE];

    const int tid = threadIdx.x;
    const int b0 = blockIdx.x * 64;

    const float kappa = fminf(fmaxf(fast_exp2(log_kappa[0] * kLOG2E), 0.5f), 50.0f);
    const float s = kappa * kLOG2E;

    // Stage Xe = clamp(exp2(s*x), 2^-14, 2^14): float4 global reads, ds_write_b128.
    const float4* xg = (const float4*)(x + (size_t)b0 * ND);
    #pragma unroll
    for (int k = 0; k < 4; ++k) {
        const int i = tid + k * 1024;       // 4096 float4s
        const float4 vv = xg[i];
        const int bb = i >> 6;
        const int cc = (i & 63) << 2;
        v4f val = { fminf(fmaxf(fast_exp2(s * vv.x), 6.1035156e-5f), 16384.0f),
                    fminf(fmaxf(fast_exp2(s * vv.y), 6.1035156e-5f), 16384.0f),
                    fminf(fmaxf(fast_exp2(s * vv.z), 6.1035156e-5f), 16384.0f),
                    fminf(fmaxf(fast_exp2(s * vv.w), 6.1035156e-5f), 16384.0f) };
        *(v4f*)(xs + bb * XS_STRIDE + cc) = val;
    }
    __syncthreads();

    const int lane = tid & 63;
    const int w = tid >> 6;
    const int r = __builtin_amdgcn_readfirstlane(blockIdx.y * 16 + w);

    // P[r] distributed: lane L covers d = 4L..4L+3 -> 4 float4 = 16 VGPRs.
    const float4* __restrict__ pbase = P4 + (size_t)r * ND + 4 * lane;
    const float4 pA = pbase[0];
    const float4 pB = pbase[1];
    const float4 pC = pbase[2];
    const float4 pD = pbase[3];

    const float baser = baseR[r];
    const float tr    = t_arr[r];
    const float hw    = head_w[r];

    const v4f* xrow4 = (const v4f*)(xs + lane * XS_STRIDE);

    float acc0 = 0.0f, acc1 = 0.0f;

    #pragma unroll 4
    for (int t = 0; t < 64; ++t) {          // iter t: d = 4t..4t+3
        const v4f X4 = xrow4[t];            // ds_read_b128 (lane's own b row)
        float4 q0, q1, q2, q3;              // broadcast lane t's params -> SGPRs
        q0.x = rl(pA.x, t); q0.y = rl(pA.y, t); q0.z = rl(pA.z, t); q0.w = rl(pA.w, t);
        q1.x = rl(pB.x, t); q1.y = rl(pB.y, t); q1.z = rl(pB.z, t); q1.w = rl(pB.w, t);
        q2.x = rl(pC.x, t); q2.y = rl(pC.y, t); q2.z = rl(pC.z, t); q2.w = rl(pC.w, t);
        q3.x = rl(pD.x, t); q3.y = rl(pD.y, t); q3.z = rl(pD.z, t); q3.w = rl(pD.w, t);
        pairstep(X4.x, X4.y, q0, q1, acc0);
        pairstep(X4.z, X4.w, q2, q3, acc1);
    }

    const float ev = baser - 2.0f * (acc0 + acc1);
    const float za = (kBETA * kLOG2E) * (tr - ev);
    const float z  = fast_rcp(1.0f + fast_exp2(za));
    const float zw = z * hw;

    // Block-level reduction over the 16 waves (16 r's), then 1 atomic per lane.
    __syncthreads();
    xs[w * 64 + lane] = zw;
    __syncthreads();
    if (w == 0) {
        float ssum = 0.0f;
        #pragma unroll
        for (int q = 0; q < 16; ++q) ssum += xs[q * 64 + lane];
        atomicAdd(&y[b0 + lane], ssum);
    }
}

extern "C" void kernel_launch(void* const* d_in, const int* in_sizes, int n_in,
                              void* d_out, int out_size, void* d_ws, size_t ws_size,
                              hipStream_t stream) {
    const float* x         = (const float*)d_in[0];
    const float* center    = (const float*)d_in[1];
    const float* log_width = (const float*)d_in[2];
    const float* e_low     = (const float*)d_in[3];
    const float* e_high    = (const float*)d_in[4];
    const float* mask      = (const float*)d_in[5];
    const float* log_kappa = (const float*)d_in[6];
    const float* t_arr     = (const float*)d_in[7];
    const float* head_w    = (const float*)d_in[8];
    const float* head_b    = (const float*)d_in[9];
    float* y = (float*)d_out;

    float4* P4   = (float4*)d_ws;                                    // 2 MB
    float* baseR = (float*)((char*)d_ws + sizeof(float4) * NR * ND); // +2 KB

    prep_kernel<<<NR, 256, 0, stream>>>(center, log_width, e_low, e_high,
                                        mask, log_kappa, head_b, P4, baseR, y);
    evid_kernel<<<dim3(NB / 64, NR / 16), 1024, 0, stream>>>(x, log_kappa, t_arr,
                                                             head_w, P4, baseR, y);
}

// Round 9
// 104.946 us; speedup vs baseline: 1.2390x; 1.2390x over previous
//
#include <hip/hip_runtime.h>
#include <math.h>

#define NB 1024
#define NR 512
#define ND 256
#define XS_STRIDE 260   // mult of 4: 16B-aligned rows for ds_read_b128; 0 conflicts measured (r6)

typedef float v4f  __attribute__((ext_vector_type(4)));
typedef float v16f __attribute__((ext_vector_type(16)));

constexpr float kBETA  = 6.0f;
constexpr float kLOG2E = 1.4426950408889634f;

#if __has_builtin(__builtin_amdgcn_exp2f)
__device__ __forceinline__ float fast_exp2(float x) { return __builtin_amdgcn_exp2f(x); }
#else
__device__ __forceinline__ float fast_exp2(float x) { return exp2f(x); }
#endif
#if __has_builtin(__builtin_amdgcn_rcpf)
__device__ __forceinline__ float fast_rcp(float x) { return __builtin_amdgcn_rcpf(x); }
#else
__device__ __forceinline__ float fast_rcp(float x) { return 1.0f / x; }
#endif

__device__ __forceinline__ float fast_sigmoid(float a) {   // 1/(1+e^-a)
    return fast_rcp(1.0f + fast_exp2(-a * kLOG2E));
}
__device__ __forceinline__ float fast_tanh(float a) {      // 1 - 2/(1+e^{2a})
    return 1.0f - 2.0f * fast_rcp(1.0f + fast_exp2(a * (2.0f * kLOG2E)));
}

// Prep: P4[r*ND+d] = {E, K, A1, A0} with b = Xe*E (separable exp):
//   E  = exp2(-s*t_high), K = exp2(-s*width)
//   element term (vs baseR): (A1*b + A0) / ((b+1)(b+K))
//   A1 = meh - mel*K, A0 = K*(meh - mel)
// baseR[r] = sum_d (meh - mel); evidence = baseR - 2*sum(term)
__global__ __launch_bounds__(256) void prep_kernel(
    const float* __restrict__ center, const float* __restrict__ log_width,
    const float* __restrict__ e_low, const float* __restrict__ e_high,
    const float* __restrict__ mask, const float* __restrict__ log_kappa,
    const float* __restrict__ head_b,
    float4* __restrict__ P4, float* __restrict__ baseR, float* __restrict__ y)
{
    const int r = blockIdx.x;
    const int d = threadIdx.x;
    const int idx = r * ND + d;

    const float kappa = fminf(fmaxf(fast_exp2(log_kappa[0] * kLOG2E), 0.5f), 50.0f);
    const float s = kappa * kLOG2E;

    const float wdt = fminf(fmaxf(fast_exp2(log_width[idx] * kLOG2E), 0.001f), 50.0f);
    const float th  = center[idx] + 0.5f * wdt;
    const float E   = fast_exp2(-s * th);
    const float K   = fmaxf(fast_exp2(-s * wdt), 1e-30f);   // floor: keeps den > 0
    const float m   = fast_sigmoid(mask[idx]);
    const float mel = m * fast_tanh(e_low[idx]);
    const float meh = m * fast_tanh(e_high[idx]);

    float4 p;
    p.x = E;
    p.y = K;
    p.z = fmaf(-mel, K, meh);      // A1
    p.w = K * (meh - mel);         // A0
    P4[idx] = p;

    float v = meh - mel;
    #pragma unroll
    for (int off = 32; off > 0; off >>= 1) v += __shfl_down(v, off, 64);
    __shared__ float red[4];
    if ((d & 63) == 0) red[d >> 6] = v;
    __syncthreads();
    if (d == 0) baseR[r] = red[0] + red[1] + red[2] + red[3];

    const int gid = blockIdx.x * 256 + threadIdx.x;
    if (gid < NB) y[gid] = head_b[0];
}

// Fused pair (2 elems, 10 VALU + 1 rcp):
//   per elem: b = X*E; q = b+K; den = q*b+q; num = A1*b+A0
//   acc += (num1*den2 + num2*den1) * rcp(den1*den2)
// Xe clamped to 2^+-14 in staging => den1*den2 bounded, no overflow.
__device__ __forceinline__ void pairstep(const float X1, const float X2,
                                         const float E1, const float K1,
                                         const float A11, const float A01,
                                         const float E2, const float K2,
                                         const float A12, const float A02,
                                         float& acc)
{
    const float b1   = X1 * E1;
    const float b2   = X2 * E2;
    const float q1   = b1 + K1;
    const float q2   = b2 + K2;
    const float den1 = fmaf(q1, b1, q1);
    const float den2 = fmaf(q2, b2, q2);
    const float num1 = fmaf(A11, b1, A01);
    const float num2 = fmaf(A12, b2, A02);
    const float nn   = fmaf(num2, den1, num1 * den2);
    const float dd   = den1 * den2;
    acc = fmaf(nn, fast_rcp(dd), acc);
}

// 4 elems from one v16f P-chunk (4 x {E,K,A1,A0}) + one v4f X chunk.
__device__ __forceinline__ void quadstep(const v4f X, const v16f P,
                                         float& acc0, float& acc1)
{
    pairstep(X.x, X.y, P[0], P[1], P[2],  P[3],  P[4],  P[5],  P[6],  P[7],  acc0);
    pairstep(X.z, X.w, P[8], P[9], P[10], P[11], P[12], P[13], P[14], P[15], acc1);
}

// Main (r6 structure, P stream widened to s_load_dwordx16):
//   1024 threads = 16 waves; wave w -> r = blockIdx.y*16 + w; lane = b.
//   Xe tile in LDS (ds_read_b128, in-lane d-reduction). P[r] read as wave-
//   uniform v16f chunks (64B scalar loads): 4x fewer K$ transactions than r6's
//   dwordx4 stream -- targets the ~1 scalar-req/cyc/CU service wall.
__global__ __launch_bounds__(1024, 8) void evid_kernel(
    const float* __restrict__ x, const float* __restrict__ log_kappa,
    const float* __restrict__ t_arr, const float* __restrict__ head_w,
    const float4* __restrict__ P4, const float* __restrict__ baseR,
    float* __restrict__ y)
{
    __shared__ float xs[64 * XS_STRIDE];

    const int tid = threadIdx.x;
    const int b0 = blockIdx.x * 64;

    const float kappa = fminf(fmaxf(fast_exp2(log_kappa[0] * kLOG2E), 0.5f), 50.0f);
    const float s = kappa * kLOG2E;

    // Stage Xe = clamp(exp2(s*x), 2^-14, 2^14): float4 global reads, ds_write_b128.
    const float4* xg = (const float4*)(x + (size_t)b0 * ND);
    #pragma unroll
    for (int k = 0; k < 4; ++k) {
        const int i = tid + k * 1024;       // 4096 float4s
        const float4 vv = xg[i];
        const int bb = i >> 6;
        const int cc = (i & 63) << 2;
        v4f val = { fminf(fmaxf(fast_exp2(s * vv.x), 6.1035156e-5f), 16384.0f),
                    fminf(fmaxf(fast_exp2(s * vv.y), 6.1035156e-5f), 16384.0f),
                    fminf(fmaxf(fast_exp2(s * vv.z), 6.1035156e-5f), 16384.0f),
                    fminf(fmaxf(fast_exp2(s * vv.w), 6.1035156e-5f), 16384.0f) };
        *(v4f*)(xs + bb * XS_STRIDE + cc) = val;
    }
    __syncthreads();

    const int lane = tid & 63;
    const int w = tid >> 6;
    const int r = __builtin_amdgcn_readfirstlane(blockIdx.y * 16 + w);

    // Wave-uniform address -> scalar loads; v16f (64B) chunks -> s_load_dwordx16.
    const v16f* __restrict__ pv = (const v16f*)(P4 + (size_t)r * ND);
    const v4f* xrow4 = (const v4f*)(xs + lane * XS_STRIDE);

    float acc0 = 0.0f, acc1 = 0.0f;

    #pragma unroll 2
    for (int t = 0; t < 32; ++t) {          // 8 d's per iter: 2 v16f + 2 ds_read_b128
        const v4f  Xa = xrow4[2 * t + 0];
        const v4f  Xb = xrow4[2 * t + 1];
        const v16f Pa = pv[2 * t + 0];
        const v16f Pb = pv[2 * t + 1];
        quadstep(Xa, Pa, acc0, acc1);
        quadstep(Xb, Pb, acc0, acc1);
    }

    const float ev = baseR[r] - 2.0f * (acc0 + acc1);
    const float za = (kBETA * kLOG2E) * (t_arr[r] - ev);
    const float z  = fast_rcp(1.0f + fast_exp2(za));
    const float zw = z * head_w[r];

    // Block-level reduction over the 16 waves (16 r's), then 1 atomic per lane.
    __syncthreads();
    xs[w * 64 + lane] = zw;
    __syncthreads();
    if (w == 0) {
        float ssum = 0.0f;
        #pragma unroll
        for (int q = 0; q < 16; ++q) ssum += xs[q * 64 + lane];
        atomicAdd(&y[b0 + lane], ssum);
    }
}

extern "C" void kernel_launch(void* const* d_in, const int* in_sizes, int n_in,
                              void* d_out, int out_size, void* d_ws, size_t ws_size,
                              hipStream_t stream) {
    const float* x         = (const float*)d_in[0];
    const float* center    = (const float*)d_in[1];
    const float* log_width = (const float*)d_in[2];
    const float* e_low     = (const float*)d_in[3];
    const float* e_high    = (const float*)d_in[4];
    const float* mask      = (const float*)d_in[5];
    const float* log_kappa = (const float*)d_in[6];
    const float* t_arr     = (const float*)d_in[7];
    const float* head_w    = (const float*)d_in[8];
    const float* head_b    = (const float*)d_in[9];
    float* y = (float*)d_out;

    float4* P4   = (float4*)d_ws;                                    // 2 MB
    float* baseR = (float*)((char*)d_ws + sizeof(float4) * NR * ND); // +2 KB

    prep_kernel<<<NR, 256, 0, stream>>>(center, log_width, e_low, e_high,
                                        mask, log_kappa, head_b, P4, baseR, y);
    evid_kernel<<<dim3(NB / 64, NR / 16), 1024, 0, stream>>>(x, log_kappa, t_arr,
                                                             head_w, P4, baseR, y);
}